// Round 1
// baseline (1569.742 us; speedup 1.0000x reference)
//
#include <hip/hip_runtime.h>
#include <math.h>

#define NTHREADS 256
#define XW_STRIDE 122   // odd word stride (61 words) -> conflict-free LDS rows

__device__ __forceinline__ float bflo(unsigned int u) {
    union { unsigned int i; float f; } v; v.i = u << 16; return v.f;
}
__device__ __forceinline__ float bfhi(unsigned int u) {
    union { unsigned int i; float f; } v; v.i = u & 0xffff0000u; return v.f;
}
__device__ __forceinline__ unsigned short f2bf(float f) {
    union { float f; unsigned int i; } v; v.f = f;
    unsigned int x = v.i;
    x += 0x7fffu + ((x >> 16) & 1u);   // round-nearest-even
    return (unsigned short)(x >> 16);
}

// stage 20 contiguous rows (2400 floats) of a weight matrix into LDS
__device__ __forceinline__ void stage_w(float* wst, const float* __restrict__ src, int tid) {
    for (int s = 0; s < 10; ++s) {
        int e = tid + NTHREADS * s;
        if (e < 2400) wst[e] = src[e];
    }
}

// compute one of k/v: out[n][d] (bf16) = xw[n] . wst[d] + bias[d], n in [0,192), d in [0,20)
__device__ __forceinline__ void compute_kv(const unsigned short* xw, const float* wst,
                                           unsigned short* kv, const float* __restrict__ qkv_b,
                                           int bias_base, int tid) {
    for (int s = 0; s < 15; ++s) {
        int e = tid + NTHREADS * s;          // e < 3840 always (15*256)
        int n = e % 192, d = e / 192;
        const unsigned short* xr = xw + n * XW_STRIDE;
        const float* wr = wst + d * 120;
        float acc = 0.f;
        for (int ch = 0; ch < 120; ch += 2) {
            unsigned int u = *(const unsigned int*)(xr + ch);
            acc += bflo(u) * wr[ch];
            acc += bfhi(u) * wr[ch + 1];
        }
        kv[n * 20 + d] = f2bf(acc + qkv_b[bias_base + d]);
    }
}

__global__ __launch_bounds__(NTHREADS, 2)
void swin_fused(const float* __restrict__ x,
                const float* __restrict__ quary0,
                const float* __restrict__ quary1,
                const float* __restrict__ qkv_w,
                const float* __restrict__ qkv_b,
                const float* __restrict__ proj_w,
                const float* __restrict__ proj_b,
                const float* __restrict__ rpb_table,
                const float* __restrict__ pm_w,
                const float* __restrict__ pm_b,
                const float* __restrict__ attn_mask,
                const int*   __restrict__ rel_idx,
                float* __restrict__ out)
{
    __shared__ unsigned short xw[192 * XW_STRIDE];  // 46848 B, window tokens bf16
    __shared__ float wst[20 * 120];                 //  9600 B, current 20 weight rows
    __shared__ unsigned short kv[192 * 20];         //  7680 B, k then v for one head
    __shared__ float pred_s[64];                    //   256 B

    const int tid  = threadIdx.x;
    const int widx = blockIdx.x;
    const int wh = widx >> 5, ww = widx & 31;
    const int r = tid >> 2, j = tid & 3;            // query row r in [0,64), quad lane j

    // ---------- phase 0: stage shifted window tokens (bf16) ----------
    for (int s = 0; s < 23; ++s) {
        int e = tid + NTHREADS * s;
        if (e < 192 * 30) {
            int n = e / 30, c4 = e % 30;
            int f = n >> 6, ii = (n >> 3) & 7, jj = n & 7;
            int y0 = (wh * 8 + ii + 4) & 255;       // roll(-4) on h
            int x0 = (ww * 8 + jj + 4) & 255;       // roll(-4) on w
            float4 val = *(const float4*)(x + (((size_t)(f * 256 + y0)) * 256 + x0) * 120 + c4 * 4);
            unsigned int lo = (unsigned)f2bf(val.x) | ((unsigned)f2bf(val.y) << 16);
            unsigned int hi = (unsigned)f2bf(val.z) | ((unsigned)f2bf(val.w) << 16);
            unsigned int off = (unsigned)(n * XW_STRIDE + c4 * 4);
            *(unsigned int*)(&xw[off])     = lo;
            *(unsigned int*)(&xw[off + 2]) = hi;
        }
    }
    // soft/pred in fp32 from GLOBAL x (sign-sensitive; do not round to bf16)
    {
        int ii = r >> 3, jj = r & 7;
        int y0 = (wh * 8 + ii + 4) & 255;
        int x0 = (ww * 8 + jj + 4) & 255;
        const float* xr  = x + (((size_t)(2 * 256 + y0)) * 256 + x0) * 120;
        const float* q0r = quary0 + ((size_t)widx * 64 + r) * 120;
        float acc = 0.f;
        for (int ch = j * 30; ch < j * 30 + 30; ++ch)
            acc += fabsf(xr[ch] - q0r[ch]) * pm_w[ch];
        acc += __shfl_xor(acc, 1);
        acc += __shfl_xor(acc, 2);
        if (j == 0) pred_s[r] = (acc + pm_b[0] >= 0.f) ? 1.f : 0.f;
    }
    __syncthreads();

    const float SCALE = 0.22360679774997896f;   // 20^-0.5
    float x1[30];
    #pragma unroll
    for (int c = 0; c < 30; ++c) x1[c] = 0.f;

    for (int h = 0; h < 6; ++h) {
        // ---- q weights ----
        stage_w(wst, qkv_w + (h * 20) * 120, tid);
        __syncthreads();

        // ---- q for row r, dims j*5..j*5+4, then share across quad ----
        float qv[5];
        {
            float a0 = 0.f, a1 = 0.f, a2 = 0.f, a3 = 0.f, a4 = 0.f;
            const unsigned short* xr = xw + (128 + r) * XW_STRIDE;
            const float* w0 = wst + (j * 5) * 120;
            for (int ch = 0; ch < 120; ch += 2) {
                unsigned int u = *(const unsigned int*)(xr + ch);
                float f0 = bflo(u), f1 = bfhi(u);
                a0 += f0 * w0[ch]       + f1 * w0[ch + 1];
                a1 += f0 * w0[120 + ch] + f1 * w0[121 + ch];
                a2 += f0 * w0[240 + ch] + f1 * w0[241 + ch];
                a3 += f0 * w0[360 + ch] + f1 * w0[361 + ch];
                a4 += f0 * w0[480 + ch] + f1 * w0[481 + ch];
            }
            int db = h * 20 + j * 5;
            qv[0] = (a0 + qkv_b[db + 0]) * SCALE;
            qv[1] = (a1 + qkv_b[db + 1]) * SCALE;
            qv[2] = (a2 + qkv_b[db + 2]) * SCALE;
            qv[3] = (a3 + qkv_b[db + 3]) * SCALE;
            qv[4] = (a4 + qkv_b[db + 4]) * SCALE;
        }
        float q20[20];
        #pragma unroll
        for (int d = 0; d < 20; ++d) {
            int src = ((tid & 63) & ~3) | (d / 5);
            q20[d] = __shfl(qv[d % 5], src);
        }
        __syncthreads();

        // ---- k ----
        stage_w(wst, qkv_w + (120 + h * 20) * 120, tid);
        __syncthreads();
        compute_kv(xw, wst, kv, qkv_b, 120 + h * 20, tid);
        __syncthreads();

        // ---- scores + softmax (thread owns n = 4m+j, m in [0,48)) ----
        float sc[48];
        const float* mrow = attn_mask + ((size_t)widx * 192 + 128 + r) * 192;
        const int*   rrow = rel_idx + r * 192;
        #pragma unroll
        for (int m = 0; m < 48; ++m) {
            int n = 4 * m + j;
            float acc = mrow[n] + rpb_table[rrow[n] * 6 + h];
            const unsigned short* kr = kv + n * 20;
            #pragma unroll
            for (int d = 0; d < 20; d += 2) {
                unsigned int u = *(const unsigned int*)(kr + d);
                acc += q20[d] * bflo(u) + q20[d + 1] * bfhi(u);
            }
            sc[m] = acc;
        }
        float mx = -1e30f;
        #pragma unroll
        for (int m = 0; m < 48; ++m) mx = fmaxf(mx, sc[m]);
        mx = fmaxf(mx, __shfl_xor(mx, 1));
        mx = fmaxf(mx, __shfl_xor(mx, 2));
        float sum = 0.f;
        #pragma unroll
        for (int m = 0; m < 48; ++m) { sc[m] = __expf(sc[m] - mx); sum += sc[m]; }
        sum += __shfl_xor(sum, 1);
        sum += __shfl_xor(sum, 2);
        float inv = 1.0f / sum;

        // ---- v weights (wst free: its last reader was compute_kv, barrier passed) ----
        stage_w(wst, qkv_w + (240 + h * 20) * 120, tid);
        __syncthreads();
        compute_kv(xw, wst, kv, qkv_b, 240 + h * 20, tid);   // overwrite k with v
        __syncthreads();

        // ---- stage proj block: wst[c*20+d] = proj_w[c][h*20+d] ----
        for (int s = 0; s < 10; ++s) {
            int e = tid + NTHREADS * s;
            if (e < 2400) {
                int c = e / 20, d = e % 20;
                wst[e] = proj_w[c * 120 + h * 20 + d];
            }
        }
        __syncthreads();

        // ---- PV + quad reduce + proj accumulation into x1 ----
        float ov[20];
        #pragma unroll
        for (int d = 0; d < 20; ++d) ov[d] = 0.f;
        #pragma unroll
        for (int m = 0; m < 48; ++m) {
            int n = 4 * m + j;
            float p = sc[m];
            const unsigned short* vr = kv + n * 20;
            #pragma unroll
            for (int d = 0; d < 20; d += 2) {
                unsigned int u = *(const unsigned int*)(vr + d);
                ov[d]     += p * bflo(u);
                ov[d + 1] += p * bfhi(u);
            }
        }
        #pragma unroll
        for (int d = 0; d < 20; ++d) {
            float v = ov[d] * inv;
            v += __shfl_xor(v, 1);
            v += __shfl_xor(v, 2);
            ov[d] = v;                    // full out[r, h*20+d] on all quad lanes
        }
        #pragma unroll
        for (int cc = 0; cc < 30; ++cc) {
            const float* pr = wst + (j * 30 + cc) * 20;
            float a = x1[cc];
            #pragma unroll
            for (int d = 0; d < 20; ++d) a += ov[d] * pr[d];
            x1[cc] = a;
        }
        __syncthreads();   // protect wst/kv before next head
    }

    // ---------- epilogue: bias, pruning blend, window-reverse + roll(+4,+4) ----------
    {
        float p = pred_s[r];
        int ii = r >> 3, jj = r & 7;
        int y0 = (wh * 8 + ii + 4) & 255;
        int x0 = (ww * 8 + jj + 4) & 255;
        float* orow = out + ((size_t)y0 * 256 + x0) * 121;
        const float* q1r = quary1 + ((size_t)widx * 64 + r) * 120;
        #pragma unroll
        for (int cc = 0; cc < 30; ++cc) {
            int c = j * 30 + cc;
            float v1 = x1[cc] + proj_b[c];
            orow[c] = (p != 0.f) ? v1 : q1r[c];
        }
        if (j == 0) orow[120] = p;
    }
}

extern "C" void kernel_launch(void* const* d_in, const int* in_sizes, int n_in,
                              void* d_out, int out_size, void* d_ws, size_t ws_size,
                              hipStream_t stream) {
    const float* x        = (const float*)d_in[0];
    const float* quary0   = (const float*)d_in[1];
    const float* quary1   = (const float*)d_in[2];
    const float* qkv_w    = (const float*)d_in[3];
    const float* qkv_b    = (const float*)d_in[4];
    const float* proj_w   = (const float*)d_in[5];
    const float* proj_b   = (const float*)d_in[6];
    const float* rpb      = (const float*)d_in[7];
    const float* pm_w     = (const float*)d_in[8];
    const float* pm_b     = (const float*)d_in[9];
    const float* attnmask = (const float*)d_in[10];
    const int*   rel_idx  = (const int*)d_in[11];
    float* out = (float*)d_out;

    swin_fused<<<1024, NTHREADS, 0, stream>>>(x, quary0, quary1, qkv_w, qkv_b,
                                              proj_w, proj_b, rpb, pm_w, pm_b,
                                              attnmask, rel_idx, out);
}

// Round 2
// 646.403 us; speedup vs baseline: 2.4284x; 2.4284x over previous
//
#include <hip/hip_runtime.h>
#include <math.h>

#define NT 512

typedef __attribute__((ext_vector_type(8))) short s16x8;
typedef __attribute__((ext_vector_type(4))) float f32x4;

__device__ __forceinline__ unsigned short f2bf(float f) {
    union { float f; unsigned int i; } v; v.f = f;
    unsigned int x = v.i;
    x += 0x7fffu + ((x >> 16) & 1u);   // round-nearest-even
    return (unsigned short)(x >> 16);
}

// load 8 contiguous fp32 from global, convert to a bf16 B/A fragment
__device__ __forceinline__ s16x8 ldBg(const float* __restrict__ p) {
    const float4* p4 = (const float4*)p;
    float4 a = p4[0], b = p4[1];
    s16x8 r;
    r[0] = (short)f2bf(a.x); r[1] = (short)f2bf(a.y);
    r[2] = (short)f2bf(a.z); r[3] = (short)f2bf(a.w);
    r[4] = (short)f2bf(b.x); r[5] = (short)f2bf(b.y);
    r[6] = (short)f2bf(b.z); r[7] = (short)f2bf(b.w);
    return r;
}

#define MFMA(a, b, c) __builtin_amdgcn_mfma_f32_16x16x32_bf16(a, b, c, 0, 0, 0)

__global__ __launch_bounds__(NT, 2)
void swin_mfma(const float* __restrict__ x,
               const float* __restrict__ quary0,
               const float* __restrict__ quary1,
               const float* __restrict__ qkv_w,
               const float* __restrict__ qkv_b,
               const float* __restrict__ proj_w,
               const float* __restrict__ proj_b,
               const float* __restrict__ rpb_table,
               const float* __restrict__ pm_w,
               const float* __restrict__ pm_b,
               const float* __restrict__ attn_mask,
               const int*   __restrict__ rel_idx,
               float* __restrict__ out)
{
    // LDS layout (bf16 everywhere, strides chosen for <=2-way bank aliasing on b128 reads)
    alignas(16) __shared__ unsigned short xw[192 * 120 + 8]; // window tokens, stride 120, +8 zero tail
    alignas(16) __shared__ unsigned short ks[192 * 40];      // k: [token][d], d 0..19, cols 20..31 zero
    alignas(16) __shared__ unsigned short vt[32 * 200];      // v^T: [d][token], rows 0..19 valid
    alignas(16) __shared__ unsigned short ps[64 * 200];      // P: [row][token] (K=192 exact)
    alignas(16) __shared__ unsigned short qs[64 * 40];       // q: [row][d], cols 20..31 zero
    alignas(16) __shared__ unsigned short os[64 * 120 + 8];  // attn out: [row][c], +8 zero tail
    __shared__ float pred_s[64];

    const int tid  = threadIdx.x;
    const int wv   = tid >> 6;        // wave 0..7
    const int ln   = tid & 63;
    const int l15  = ln & 15;
    const int qd   = ln >> 4;         // quad 0..3
    const int widx = blockIdx.x;
    const int wh = widx >> 5, ww = widx & 31;
    const float SCALE = 0.22360679774997896f;   // 20^-0.5

    // ---------------- phase 0: staging ----------------
    for (int e = tid; e < 192 * 30; e += NT) {
        int n = e / 30, c4 = e % 30;
        int f = n >> 6, ii = (n >> 3) & 7, jj = n & 7;
        int y0 = (wh * 8 + ii + 4) & 255;
        int x0 = (ww * 8 + jj + 4) & 255;
        float4 val = *(const float4*)(x + (((size_t)(f * 256 + y0)) * 256 + x0) * 120 + c4 * 4);
        unsigned int lo = (unsigned)f2bf(val.x) | ((unsigned)f2bf(val.y) << 16);
        unsigned int hi = (unsigned)f2bf(val.z) | ((unsigned)f2bf(val.w) << 16);
        unsigned int off = (unsigned)(n * 120 + c4 * 4);
        *(unsigned int*)(xw + off)     = lo;
        *(unsigned int*)(xw + off + 2) = hi;
    }
    if (tid < 8) xw[192 * 120 + tid] = 0;
    if (tid < 8) os[64 * 120 + tid] = 0;
    for (int e = tid; e < 192 * 12; e += NT) ks[(e / 12) * 40 + 20 + (e % 12)] = 0;
    for (int e = tid; e < 64 * 12;  e += NT) qs[(e / 12) * 40 + 20 + (e % 12)] = 0;
    // pred in exact fp32 (sign-sensitive): threads 0..255, quad per query row
    if (tid < 256) {
        int r = tid >> 2, j = tid & 3;
        int ii = r >> 3, jj = r & 7;
        int y0 = (wh * 8 + ii + 4) & 255;
        int x0 = (ww * 8 + jj + 4) & 255;
        const float* xr  = x + (((size_t)(2 * 256 + y0)) * 256 + x0) * 120;
        const float* q0r = quary0 + ((size_t)widx * 64 + r) * 120;
        float acc = 0.f;
        for (int ch = j * 30; ch < j * 30 + 30; ++ch)
            acc += fabsf(xr[ch] - q0r[ch]) * pm_w[ch];
        acc += __shfl_xor(acc, 1);
        acc += __shfl_xor(acc, 2);
        if (j == 0) pred_s[r] = (acc + pm_b[0] >= 0.f) ? 1.f : 0.f;
    }
    __syncthreads();

    // ---------------- head loop ----------------
    for (int h = 0; h < 6; ++h) {
        // ---- K/V GEMM: M=192 (12 mt), N=48 (3 nt: k 0..19 | v 0..19 | pad), K=120(pad 128) ----
        for (int e = wv; e < 36; e += 8) {
            int mt = e % 12, nt = e / 12;
            int nglob = nt * 16 + l15;          // 0..47
            int wrow = 0; bool vld = true;
            if (nglob < 20)      wrow = 120 + h * 20 + nglob;
            else if (nglob < 40) wrow = 240 + h * 20 + (nglob - 20);
            else                 vld = false;
            f32x4 acc = {0.f, 0.f, 0.f, 0.f};
            const unsigned short* arow = xw + (mt * 16 + l15) * 120;
            #pragma unroll
            for (int kk = 0; kk < 4; ++kk) {
                int kst = kk * 32 + qd * 8;
                s16x8 aF = *(const s16x8*)(arow + kst);
                s16x8 bF;
                if (vld && kst < 120) bF = ldBg(qkv_w + (size_t)wrow * 120 + kst);
                else { s16x8 z = {0,0,0,0,0,0,0,0}; bF = z; }
                acc = MFMA(aF, bF, acc);
            }
            if (nglob < 40) {
                float bias = qkv_b[nglob < 20 ? (120 + h * 20 + nglob)
                                              : (240 + h * 20 + (nglob - 20))];
                #pragma unroll
                for (int reg = 0; reg < 4; ++reg) {
                    int tok = mt * 16 + qd * 4 + reg;
                    unsigned short vb = f2bf(acc[reg] + bias);
                    if (nglob < 20) ks[tok * 40 + nglob] = vb;
                    else            vt[(nglob - 20) * 200 + tok] = vb;
                }
            }
        }
        // ---- q GEMM on waves 4..7: M=64 (4 mt), N=20(pad 32, 2 nt), K=120(pad 128) ----
        if (wv >= 4) {
            for (int e2 = (wv - 4) * 2; e2 < (wv - 4) * 2 + 2; ++e2) {
                int mt = e2 & 3, nt = e2 >> 2;
                int nn = nt * 16 + l15;         // 0..31 ; rows h*20+nn <= 131 always valid mem
                int wrow = h * 20 + nn;
                f32x4 acc = {0.f, 0.f, 0.f, 0.f};
                const unsigned short* arow = xw + (128 + mt * 16 + l15) * 120;
                #pragma unroll
                for (int kk = 0; kk < 4; ++kk) {
                    int kst = kk * 32 + qd * 8;
                    s16x8 aF = *(const s16x8*)(arow + kst);
                    s16x8 bF;
                    if (kst < 120) bF = ldBg(qkv_w + (size_t)wrow * 120 + kst);
                    else { s16x8 z = {0,0,0,0,0,0,0,0}; bF = z; }
                    acc = MFMA(aF, bF, acc);
                }
                if (nn < 20) {
                    float bias = qkv_b[h * 20 + nn];
                    #pragma unroll
                    for (int reg = 0; reg < 4; ++reg)
                        qs[(mt * 16 + qd * 4 + reg) * 40 + nn] = f2bf(acc[reg] + bias);
                }
            }
        }
        __syncthreads();

        // ---- scores QK^T + softmax: waves 0..3, wave = mt (16 query rows each) ----
        if (wv < 4) {
            const int mt = wv;
            f32x4 sc[12];
            s16x8 aF = *(const s16x8*)(qs + (mt * 16 + l15) * 40 + qd * 8);
            #pragma unroll
            for (int nt = 0; nt < 12; ++nt) {
                s16x8 bF = *(const s16x8*)(ks + (nt * 16 + l15) * 40 + qd * 8);
                f32x4 z = {0.f, 0.f, 0.f, 0.f};
                sc[nt] = MFMA(aF, bF, z);
            }
            const int rbase = mt * 16 + qd * 4;
            #pragma unroll
            for (int reg = 0; reg < 4; ++reg) {
                int r = rbase + reg;
                const float* mrow = attn_mask + (size_t)widx * 36864 + (size_t)(128 + r) * 192;
                const int*   rrow = rel_idx + r * 192;
                #pragma unroll
                for (int nt = 0; nt < 12; ++nt) {
                    int n = nt * 16 + l15;
                    sc[nt][reg] = sc[nt][reg] * SCALE + mrow[n] + rpb_table[rrow[n] * 6 + h];
                }
                float mx = -1e30f;
                #pragma unroll
                for (int nt = 0; nt < 12; ++nt) mx = fmaxf(mx, sc[nt][reg]);
                mx = fmaxf(mx, __shfl_xor(mx, 1));
                mx = fmaxf(mx, __shfl_xor(mx, 2));
                mx = fmaxf(mx, __shfl_xor(mx, 4));
                mx = fmaxf(mx, __shfl_xor(mx, 8));
                float sum = 0.f;
                #pragma unroll
                for (int nt = 0; nt < 12; ++nt) {
                    float ev = __expf(sc[nt][reg] - mx);
                    sc[nt][reg] = ev; sum += ev;
                }
                sum += __shfl_xor(sum, 1);
                sum += __shfl_xor(sum, 2);
                sum += __shfl_xor(sum, 4);
                sum += __shfl_xor(sum, 8);
                float inv = 1.0f / sum;
                #pragma unroll
                for (int nt = 0; nt < 12; ++nt)
                    ps[r * 200 + nt * 16 + l15] = f2bf(sc[nt][reg] * inv);
            }
        }
        __syncthreads();

        // ---- PV: M=64 (4 mt), N=20(pad 32, 2 nt), K=192 (6 ksteps); 1 tile per wave ----
        {
            int mt = wv & 3, nt = wv >> 2;
            f32x4 acc = {0.f, 0.f, 0.f, 0.f};
            const unsigned short* prow = ps + (mt * 16 + l15) * 200;
            const unsigned short* vrow = vt + (nt * 16 + l15) * 200;
            #pragma unroll
            for (int kk = 0; kk < 6; ++kk) {
                s16x8 aF = *(const s16x8*)(prow + kk * 32 + qd * 8);
                s16x8 bF = *(const s16x8*)(vrow + kk * 32 + qd * 8);
                acc = MFMA(aF, bF, acc);
            }
            int d = nt * 16 + l15;
            if (d < 20) {
                #pragma unroll
                for (int reg = 0; reg < 4; ++reg)
                    os[(mt * 16 + qd * 4 + reg) * 120 + h * 20 + d] = f2bf(acc[reg]);
            }
        }
        __syncthreads();   // protect ks/vt/qs/ps rewrite next head; os ready for proj after h=5
    }

    // ---------------- proj GEMM + blend + scatter: M=64, N=120(pad 128), K=120(pad 128) ----
    for (int e = wv; e < 32; e += 8) {
        int mt = e & 3, nt = e >> 2;
        int c = nt * 16 + l15;
        bool cv = (c < 120);
        f32x4 acc = {0.f, 0.f, 0.f, 0.f};
        const unsigned short* arow = os + (mt * 16 + l15) * 120;
        #pragma unroll
        for (int kk = 0; kk < 4; ++kk) {
            int kst = kk * 32 + qd * 8;
            s16x8 aF = *(const s16x8*)(arow + kst);
            s16x8 bF;
            if (cv && kst < 120) bF = ldBg(proj_w + (size_t)c * 120 + kst);
            else { s16x8 z = {0,0,0,0,0,0,0,0}; bF = z; }
            acc = MFMA(aF, bF, acc);
        }
        if (cv) {
            float pb = proj_b[c];
            #pragma unroll
            for (int reg = 0; reg < 4; ++reg) {
                int r = mt * 16 + qd * 4 + reg;
                float p = pred_s[r];
                float val = acc[reg] + pb;
                int ii = r >> 3, jj = r & 7;
                int y0 = (wh * 8 + ii + 4) & 255;
                int x0 = (ww * 8 + jj + 4) & 255;
                float fin = (p != 0.f) ? val
                                       : quary1[(size_t)widx * 7680 + (size_t)r * 120 + c];
                out[((size_t)(y0 * 256 + x0)) * 121 + c] = fin;
            }
        }
    }
    // pred channel
    if (tid < 64) {
        int r = tid;
        int ii = r >> 3, jj = r & 7;
        int y0 = (wh * 8 + ii + 4) & 255;
        int x0 = (ww * 8 + jj + 4) & 255;
        out[((size_t)(y0 * 256 + x0)) * 121 + 120] = pred_s[r];
    }
}

extern "C" void kernel_launch(void* const* d_in, const int* in_sizes, int n_in,
                              void* d_out, int out_size, void* d_ws, size_t ws_size,
                              hipStream_t stream) {
    const float* x        = (const float*)d_in[0];
    const float* quary0   = (const float*)d_in[1];
    const float* quary1   = (const float*)d_in[2];
    const float* qkv_w    = (const float*)d_in[3];
    const float* qkv_b    = (const float*)d_in[4];
    const float* proj_w   = (const float*)d_in[5];
    const float* proj_b   = (const float*)d_in[6];
    const float* rpb      = (const float*)d_in[7];
    const float* pm_w     = (const float*)d_in[8];
    const float* pm_b     = (const float*)d_in[9];
    const float* attnmask = (const float*)d_in[10];
    const int*   rel_idx  = (const int*)d_in[11];
    float* out = (float*)d_out;

    swin_mfma<<<1024, NT, 0, stream>>>(x, quary0, quary1, qkv_w, qkv_b,
                                       proj_w, proj_b, rpb, pm_w, pm_b,
                                       attnmask, rel_idx, out);
}

// Round 3
// 516.976 us; speedup vs baseline: 3.0364x; 1.2504x over previous
//
#include <hip/hip_runtime.h>
#include <math.h>

#define NT 512

typedef __attribute__((ext_vector_type(8))) short s16x8;
typedef __attribute__((ext_vector_type(4))) float f32x4;

// d_ws layout (bytes)
#define KVF_OFF 0        // bf16 KV B-frags: [h][nt3][kk4][512]   -> 73728 B
#define QF_OFF  73728    // bf16 q  B-frags: [h][nt2][kk4][512]   -> 49152 B
#define PJF_OFF 122880   // bf16 proj B-frags: [nt8][kk4][512]    -> 32768 B
#define RPB_OFF 155648   // fp32 rpb6: [h][r64][n192]             -> 294912 B

__device__ __forceinline__ unsigned short f2bf(float f) {
    union { float f; unsigned int i; } v; v.f = f;
    unsigned int x = v.i;
    x += 0x7fffu + ((x >> 16) & 1u);   // round-nearest-even
    return (unsigned short)(x >> 16);
}

#define MFMA(a, b, c) __builtin_amdgcn_mfma_f32_16x16x32_bf16(a, b, c, 0, 0, 0)

// ---------------- prep: weights -> bf16 fragments, rpb gathered ----------------
__global__ void prep(const float* __restrict__ qkv_w,
                     const float* __restrict__ proj_w,
                     const float* __restrict__ rpb_table,
                     const int*   __restrict__ rel_idx,
                     unsigned char* __restrict__ wsb)
{
    int gid = blockIdx.x * blockDim.x + threadIdx.x;
    int nthr = gridDim.x * blockDim.x;
    unsigned short* KVF = (unsigned short*)(wsb + KVF_OFF);
    unsigned short* QF  = (unsigned short*)(wsb + QF_OFF);
    unsigned short* PJF = (unsigned short*)(wsb + PJF_OFF);
    float*          RPB = (float*)(wsb + RPB_OFF);

    // KV fragments: f = ((h*3+nt)*4+kk)*512 + ln*8 + j
    for (int f = gid; f < 6 * 3 * 4 * 512; f += nthr) {
        int q = f & 511, rest = f >> 9;
        int kk = rest & 3, rest2 = rest >> 2;
        int nt = rest2 % 3, h = rest2 / 3;
        int ln = q >> 3, j = q & 7;
        int l15 = ln & 15, qd = ln >> 4;
        int nglob = nt * 16 + l15, k = kk * 32 + qd * 8 + j;
        float v = 0.f;
        if (k < 120 && nglob < 40) {
            int row = (nglob < 20) ? (120 + h * 20 + nglob) : (240 + h * 20 + nglob - 20);
            v = qkv_w[row * 120 + k];
        }
        KVF[f] = f2bf(v);
    }
    // q fragments: f = ((h*2+nt)*4+kk)*512 + ln*8 + j   (cols >=20 garbage-ok, k>=120 zero)
    for (int f = gid; f < 6 * 2 * 4 * 512; f += nthr) {
        int q = f & 511, rest = f >> 9;
        int kk = rest & 3, rest2 = rest >> 2;
        int nt = rest2 & 1, h = rest2 >> 1;
        int ln = q >> 3, j = q & 7;
        int l15 = ln & 15, qd = ln >> 4;
        int nn = nt * 16 + l15, k = kk * 32 + qd * 8 + j;
        int row = h * 20 + nn;                    // <=131, always valid memory
        float v = (k < 120) ? qkv_w[row * 120 + k] : 0.f;
        QF[f] = f2bf(v);
    }
    // proj fragments: f = (nt*4+kk)*512 + ln*8 + j
    for (int f = gid; f < 8 * 4 * 512; f += nthr) {
        int q = f & 511, rest = f >> 9;
        int kk = rest & 3, nt = rest >> 2;
        int ln = q >> 3, j = q & 7;
        int l15 = ln & 15, qd = ln >> 4;
        int c = nt * 16 + l15, k = kk * 32 + qd * 8 + j;
        float v = (k < 120 && c < 120) ? proj_w[c * 120 + k] : 0.f;
        PJF[f] = f2bf(v);
    }
    // rpb6 gathered: [h][r][n] fp32
    for (int i = gid; i < 6 * 64 * 192; i += nthr) {
        int n = i % 192, r = (i / 192) % 64, h = i / (192 * 64);
        RPB[i] = rpb_table[rel_idx[r * 192 + n] * 6 + h];
    }
}

// ---------------- main fused kernel ----------------
__global__ __launch_bounds__(NT, 2)
void swin_mfma(const float* __restrict__ x,
               const float* __restrict__ quary0,
               const float* __restrict__ quary1,
               const float* __restrict__ qkv_b,
               const float* __restrict__ proj_b,
               const float* __restrict__ pm_w,
               const float* __restrict__ pm_b,
               const float* __restrict__ attn_mask,
               const unsigned char* __restrict__ wsb,
               float* __restrict__ out)
{
    alignas(16) __shared__ unsigned short xw[192 * 120 + 8]; // window tokens bf16
    alignas(16) __shared__ unsigned short ks[192 * 40];      // k:[token][d], cols 20..31 zero
    alignas(16) __shared__ unsigned short vt[32 * 200];      // v^T:[d][token], rows 20..31 garbage-ok
    alignas(16) __shared__ unsigned short ps[64 * 200];      // P:[row][token]
    alignas(16) __shared__ unsigned short qs[64 * 40];       // q:[row][d], cols 20..31 zero
    alignas(16) __shared__ unsigned short os[64 * 120 + 8];  // attn out:[row][c]
    __shared__ float2 red[64][2];                            // softmax partials {max,sum}
    __shared__ float pred_s[64];

    const int tid = threadIdx.x;
    const int wv = tid >> 6, ln = tid & 63;
    const int l15 = ln & 15, qd = ln >> 4;
    const int widx = blockIdx.x;
    const int wh = widx >> 5, ww = widx & 31;
    const float SCALE = 0.22360679774997896f;   // 20^-0.5

    const unsigned short* KVF = (const unsigned short*)(wsb + KVF_OFF);
    const unsigned short* QF  = (const unsigned short*)(wsb + QF_OFF);
    const unsigned short* PJF = (const unsigned short*)(wsb + PJF_OFF);
    const float*          RPB = (const float*)(wsb + RPB_OFF);

    // ---------------- staging ----------------
    for (int e = tid; e < 192 * 30; e += NT) {
        int n = e / 30, c4 = e % 30;
        int f = n >> 6, ii = (n >> 3) & 7, jj = n & 7;
        int y0 = (wh * 8 + ii + 4) & 255;
        int x0 = (ww * 8 + jj + 4) & 255;
        float4 val = *(const float4*)(x + (((size_t)(f * 256 + y0)) * 256 + x0) * 120 + c4 * 4);
        unsigned int lo = (unsigned)f2bf(val.x) | ((unsigned)f2bf(val.y) << 16);
        unsigned int hi = (unsigned)f2bf(val.z) | ((unsigned)f2bf(val.w) << 16);
        unsigned int off = (unsigned)(n * 120 + c4 * 4);
        *(unsigned int*)(xw + off)     = lo;
        *(unsigned int*)(xw + off + 2) = hi;
    }
    if (tid < 8) xw[192 * 120 + tid] = 0;
    if (tid < 8) os[64 * 120 + tid] = 0;
    for (int e = tid; e < 192 * 12; e += NT) ks[(e / 12) * 40 + 20 + (e % 12)] = 0;
    for (int e = tid; e < 64 * 12;  e += NT) qs[(e / 12) * 40 + 20 + (e % 12)] = 0;
    // pred in exact fp32 (sign-sensitive)
    if (tid < 256) {
        int r = tid >> 2, j = tid & 3;
        int ii = r >> 3, jj = r & 7;
        int y0 = (wh * 8 + ii + 4) & 255;
        int x0 = (ww * 8 + jj + 4) & 255;
        const float* xr  = x + (((size_t)(2 * 256 + y0)) * 256 + x0) * 120;
        const float* q0r = quary0 + ((size_t)widx * 64 + r) * 120;
        float acc = 0.f;
        for (int ch = j * 30; ch < j * 30 + 30; ++ch)
            acc += fabsf(xr[ch] - q0r[ch]) * pm_w[ch];
        acc += __shfl_xor(acc, 1);
        acc += __shfl_xor(acc, 2);
        if (j == 0) pred_s[r] = (acc + pm_b[0] >= 0.f) ? 1.f : 0.f;
    }
    __syncthreads();

    // ---------------- head loop ----------------
    for (int h = 0; h < 6; ++h) {
        // ---- phase A: 36 KV tiles + 8 q tiles, balanced over 8 waves ----
        for (int e = wv; e < 44; e += 8) {
            if (e < 36) {
                int mt = e % 12, nt = e / 12;
                const unsigned short* arow  = xw + (mt * 16 + l15) * 120;
                const unsigned short* bbase = KVF + ((h * 3 + nt) * 4) * 512 + ln * 8;
                f32x4 acc = {0.f, 0.f, 0.f, 0.f};
                #pragma unroll
                for (int kk = 0; kk < 4; ++kk) {
                    s16x8 aF = *(const s16x8*)(arow + kk * 32 + qd * 8);
                    s16x8 bF = *(const s16x8*)(bbase + kk * 512);
                    acc = MFMA(aF, bF, acc);
                }
                int nglob = nt * 16 + l15;
                if (nglob < 40) {
                    float bias = qkv_b[nglob < 20 ? (120 + h * 20 + nglob)
                                                  : (240 + h * 20 + nglob - 20)];
                    #pragma unroll
                    for (int reg = 0; reg < 4; ++reg) {
                        int tok = mt * 16 + qd * 4 + reg;
                        unsigned short vb = f2bf(acc[reg] + bias);
                        if (nglob < 20) ks[tok * 40 + nglob] = vb;
                        else            vt[(nglob - 20) * 200 + tok] = vb;
                    }
                }
            } else {
                int t = e - 36, mt = t & 3, nt = t >> 2;
                const unsigned short* arow  = xw + (128 + mt * 16 + l15) * 120;
                const unsigned short* bbase = QF + ((h * 2 + nt) * 4) * 512 + ln * 8;
                f32x4 acc = {0.f, 0.f, 0.f, 0.f};
                #pragma unroll
                for (int kk = 0; kk < 4; ++kk) {
                    s16x8 aF = *(const s16x8*)(arow + kk * 32 + qd * 8);
                    s16x8 bF = *(const s16x8*)(bbase + kk * 512);
                    acc = MFMA(aF, bF, acc);
                }
                int nn = nt * 16 + l15;
                if (nn < 20) {
                    float bias = qkv_b[h * 20 + nn];
                    #pragma unroll
                    for (int reg = 0; reg < 4; ++reg)
                        qs[(mt * 16 + qd * 4 + reg) * 40 + nn] = f2bf((acc[reg] + bias) * SCALE);
                }
            }
        }
        __syncthreads();

        // ---- phase B: scores + softmax, ALL 8 waves (wave = (mt, col-half)) ----
        {
            int mt = wv & 3, hf = wv >> 2;
            f32x4 sc[6];
            s16x8 aF = *(const s16x8*)(qs + (mt * 16 + l15) * 40 + qd * 8);
            #pragma unroll
            for (int t = 0; t < 6; ++t) {
                int nt = hf * 6 + t;
                s16x8 bF = *(const s16x8*)(ks + (nt * 16 + l15) * 40 + qd * 8);
                f32x4 z = {0.f, 0.f, 0.f, 0.f};
                sc[t] = MFMA(aF, bF, z);
            }
            float ex[4][6], mh[4];
            #pragma unroll
            for (int reg = 0; reg < 4; ++reg) {
                int r = mt * 16 + qd * 4 + reg;
                const float* mrow = attn_mask + (size_t)widx * 36864 + (size_t)(128 + r) * 192;
                const float* rrow = RPB + (size_t)(h * 64 + r) * 192;
                float m = -1e30f;
                #pragma unroll
                for (int t = 0; t < 6; ++t) {
                    int n = (hf * 6 + t) * 16 + l15;
                    float v = sc[t][reg] + mrow[n] + rrow[n];
                    sc[t][reg] = v;
                    m = fmaxf(m, v);
                }
                m = fmaxf(m, __shfl_xor(m, 1));
                m = fmaxf(m, __shfl_xor(m, 2));
                m = fmaxf(m, __shfl_xor(m, 4));
                m = fmaxf(m, __shfl_xor(m, 8));
                float s = 0.f;
                #pragma unroll
                for (int t = 0; t < 6; ++t) {
                    float e2 = __expf(sc[t][reg] - m);
                    ex[reg][t] = e2; s += e2;
                }
                s += __shfl_xor(s, 1);
                s += __shfl_xor(s, 2);
                s += __shfl_xor(s, 4);
                s += __shfl_xor(s, 8);
                mh[reg] = m;
                if (l15 == 0) red[r][hf] = make_float2(m, s);
            }
            __syncthreads();
            #pragma unroll
            for (int reg = 0; reg < 4; ++reg) {
                int r = mt * 16 + qd * 4 + reg;
                float2 p0 = red[r][0], p1 = red[r][1];
                float M = fmaxf(p0.x, p1.x);
                float S = p0.y * __expf(p0.x - M) + p1.y * __expf(p1.x - M);
                float fac = __expf(mh[reg] - M) / S;
                #pragma unroll
                for (int t = 0; t < 6; ++t)
                    ps[r * 200 + (hf * 6 + t) * 16 + l15] = f2bf(ex[reg][t] * fac);
            }
        }
        __syncthreads();

        // ---- phase C: PV, one tile per wave ----
        {
            int mt = wv & 3, nt = wv >> 2;
            const unsigned short* prow = ps + (mt * 16 + l15) * 200;
            const unsigned short* vrow = vt + (nt * 16 + l15) * 200;
            f32x4 acc = {0.f, 0.f, 0.f, 0.f};
            #pragma unroll
            for (int kk = 0; kk < 6; ++kk) {
                s16x8 aF = *(const s16x8*)(prow + kk * 32 + qd * 8);
                s16x8 bF = *(const s16x8*)(vrow + kk * 32 + qd * 8);
                acc = MFMA(aF, bF, acc);
            }
            int d = nt * 16 + l15;
            if (d < 20) {
                #pragma unroll
                for (int reg = 0; reg < 4; ++reg)
                    os[(mt * 16 + qd * 4 + reg) * 120 + h * 20 + d] = f2bf(acc[reg]);
            }
        }
        __syncthreads();
    }

    // ---------------- proj + blend + scatter ----------------
    for (int e = wv; e < 32; e += 8) {
        int mt = e & 3, nt = e >> 2;
        int c = nt * 16 + l15;
        const unsigned short* arow  = os + (mt * 16 + l15) * 120;
        const unsigned short* bbase = PJF + (nt * 4) * 512 + ln * 8;
        f32x4 acc = {0.f, 0.f, 0.f, 0.f};
        #pragma unroll
        for (int kk = 0; kk < 4; ++kk) {
            s16x8 aF = *(const s16x8*)(arow + kk * 32 + qd * 8);
            s16x8 bF = *(const s16x8*)(bbase + kk * 512);
            acc = MFMA(aF, bF, acc);
        }
        if (c < 120) {
            float pb = proj_b[c];
            #pragma unroll
            for (int reg = 0; reg < 4; ++reg) {
                int r = mt * 16 + qd * 4 + reg;
                float p = pred_s[r];
                int ii = r >> 3, jj = r & 7;
                int y0 = (wh * 8 + ii + 4) & 255;
                int x0 = (ww * 8 + jj + 4) & 255;
                float fin = (p != 0.f) ? (acc[reg] + pb)
                                       : quary1[(size_t)widx * 7680 + (size_t)r * 120 + c];
                out[((size_t)(y0 * 256 + x0)) * 121 + c] = fin;
            }
        }
    }
    if (tid < 64) {
        int r = tid;
        int ii = r >> 3, jj = r & 7;
        int y0 = (wh * 8 + ii + 4) & 255;
        int x0 = (ww * 8 + jj + 4) & 255;
        out[((size_t)(y0 * 256 + x0)) * 121 + 120] = pred_s[r];
    }
}

extern "C" void kernel_launch(void* const* d_in, const int* in_sizes, int n_in,
                              void* d_out, int out_size, void* d_ws, size_t ws_size,
                              hipStream_t stream) {
    const float* x        = (const float*)d_in[0];
    const float* quary0   = (const float*)d_in[1];
    const float* quary1   = (const float*)d_in[2];
    const float* qkv_w    = (const float*)d_in[3];
    const float* qkv_b    = (const float*)d_in[4];
    const float* proj_w   = (const float*)d_in[5];
    const float* proj_b   = (const float*)d_in[6];
    const float* rpb      = (const float*)d_in[7];
    const float* pm_w     = (const float*)d_in[8];
    const float* pm_b     = (const float*)d_in[9];
    const float* attnmask = (const float*)d_in[10];
    const int*   rel_idx  = (const int*)d_in[11];
    float* out = (float*)d_out;
    unsigned char* wsb = (unsigned char*)d_ws;

    prep<<<128, 512, 0, stream>>>(qkv_w, proj_w, rpb, rel_idx, wsb);
    swin_mfma<<<1024, NT, 0, stream>>>(x, quary0, quary1, qkv_b, proj_b,
                                       pm_w, pm_b, attnmask, wsb, out);
}

// Round 4
// 501.188 us; speedup vs baseline: 3.1320x; 1.0315x over previous
//
#include <hip/hip_runtime.h>
#include <math.h>

#define NT 512

typedef __attribute__((ext_vector_type(8))) short s16x8;
typedef __attribute__((ext_vector_type(4))) float f32x4;

// d_ws layout (bytes)
#define KVF_OFF 0        // bf16 KV B-frags: [h][nt3][kk4][512]   -> 73728 B
#define QF_OFF  73728    // bf16 q  B-frags: [h][nt2][kk4][512]   -> 49152 B
#define PJF_OFF 122880   // bf16 proj B-frags: [h][nt8][512] K=32 -> 49152 B
#define RPB_OFF 172032   // fp32 rpb6: [h][r64][n192]             -> 294912 B

__device__ __forceinline__ unsigned short f2bf(float f) {
    union { float f; unsigned int i; } v; v.f = f;
    unsigned int x = v.i;
    x += 0x7fffu + ((x >> 16) & 1u);   // round-nearest-even
    return (unsigned short)(x >> 16);
}

#define MFMA(a, b, c) __builtin_amdgcn_mfma_f32_16x16x32_bf16(a, b, c, 0, 0, 0)

// ---------------- prep: weights -> bf16 fragments, rpb gathered ----------------
__global__ void prep(const float* __restrict__ qkv_w,
                     const float* __restrict__ proj_w,
                     const float* __restrict__ rpb_table,
                     const int*   __restrict__ rel_idx,
                     unsigned char* __restrict__ wsb)
{
    int gid = blockIdx.x * blockDim.x + threadIdx.x;
    int nthr = gridDim.x * blockDim.x;
    unsigned short* KVF = (unsigned short*)(wsb + KVF_OFF);
    unsigned short* QF  = (unsigned short*)(wsb + QF_OFF);
    unsigned short* PJF = (unsigned short*)(wsb + PJF_OFF);
    float*          RPB = (float*)(wsb + RPB_OFF);

    // KV fragments: f = ((h*3+nt)*4+kk)*512 + ln*8 + j
    for (int f = gid; f < 6 * 3 * 4 * 512; f += nthr) {
        int q = f & 511, rest = f >> 9;
        int kk = rest & 3, rest2 = rest >> 2;
        int nt = rest2 % 3, h = rest2 / 3;
        int ln = q >> 3, j = q & 7;
        int l15 = ln & 15, qd = ln >> 4;
        int nglob = nt * 16 + l15, k = kk * 32 + qd * 8 + j;
        float v = 0.f;
        if (k < 120 && nglob < 40) {
            int row = (nglob < 20) ? (120 + h * 20 + nglob) : (240 + h * 20 + nglob - 20);
            v = qkv_w[row * 120 + k];
        }
        KVF[f] = f2bf(v);
    }
    // q fragments: f = ((h*2+nt)*4+kk)*512 + ln*8 + j
    for (int f = gid; f < 6 * 2 * 4 * 512; f += nthr) {
        int q = f & 511, rest = f >> 9;
        int kk = rest & 3, rest2 = rest >> 2;
        int nt = rest2 & 1, h = rest2 >> 1;
        int ln = q >> 3, j = q & 7;
        int l15 = ln & 15, qd = ln >> 4;
        int nn = nt * 16 + l15, k = kk * 32 + qd * 8 + j;
        int row = h * 20 + nn;                    // <=131, always valid memory
        float v = (k < 120) ? qkv_w[row * 120 + k] : 0.f;
        QF[f] = f2bf(v);
    }
    // proj fragments, per-head K=32 slice: f = ((h*8+nt))*512 + ln*8 + j
    for (int f = gid; f < 6 * 8 * 512; f += nthr) {
        int q = f & 511, rest = f >> 9;
        int nt = rest & 7, h = rest >> 3;
        int ln = q >> 3, j = q & 7;
        int l15 = ln & 15, qd = ln >> 4;
        int c = nt * 16 + l15, k = qd * 8 + j;    // k = d within head, 0..31
        float v = (k < 20 && c < 120) ? proj_w[c * 120 + h * 20 + k] : 0.f;
        PJF[f] = f2bf(v);
    }
    // rpb6 gathered: [h][r][n] fp32
    for (int i = gid; i < 6 * 64 * 192; i += nthr) {
        int n = i % 192, r = (i / 192) % 64, h = i / (192 * 64);
        RPB[i] = rpb_table[rel_idx[r * 192 + n] * 6 + h];
    }
}

// ---------------- main fused kernel (head-pipelined) ----------------
__global__ __launch_bounds__(NT, 2)
void swin_mfma(const float* __restrict__ x,
               const float* __restrict__ quary0,
               const float* __restrict__ quary1,
               const float* __restrict__ qkv_b,
               const float* __restrict__ proj_b,
               const float* __restrict__ pm_w,
               const float* __restrict__ pm_b,
               const unsigned char* __restrict__ wsb,
               float* __restrict__ out)
{
    alignas(16) __shared__ unsigned short xw[192 * 120 + 8]; // window tokens bf16
    alignas(16) __shared__ unsigned short ks[192 * 40];      // k:[tok][d], cols 20..31 zero
    alignas(16) __shared__ unsigned short vt[2 * 32 * 200];  // v^T:[d][tok], dbuf by head parity
    alignas(16) __shared__ unsigned short ps[2 * 64 * 200];  // P:[row][tok], dbuf by head parity
    alignas(16) __shared__ unsigned short qs[64 * 40];       // q:[row][d], cols 20..31 zero
    alignas(16) __shared__ unsigned short oh[64 * 40];       // per-head O:[row][d], cols 20..31 zero
    __shared__ float pred_s[64];
    __shared__ int grp_s[64];                                // Swin region id per spatial pos

    const int tid = threadIdx.x;
    const int wv = tid >> 6, ln = tid & 63;
    const int l15 = ln & 15, qd = ln >> 4;
    const int widx = blockIdx.x;
    const int wh = widx >> 5, ww = widx & 31;
    const float SCALE = 0.22360679774997896f;   // 20^-0.5

    const unsigned short* KVF = (const unsigned short*)(wsb + KVF_OFF);
    const unsigned short* QF  = (const unsigned short*)(wsb + QF_OFF);
    const unsigned short* PJF = (const unsigned short*)(wsb + PJF_OFF);
    const float*          RPB = (const float*)(wsb + RPB_OFF);

    // ---------------- staging ----------------
    for (int e = tid; e < 192 * 30; e += NT) {
        int n = e / 30, c4 = e % 30;
        int f = n >> 6, ii = (n >> 3) & 7, jj = n & 7;
        int y0 = (wh * 8 + ii + 4) & 255;
        int x0 = (ww * 8 + jj + 4) & 255;
        float4 val = *(const float4*)(x + (((size_t)(f * 256 + y0)) * 256 + x0) * 120 + c4 * 4);
        unsigned int lo = (unsigned)f2bf(val.x) | ((unsigned)f2bf(val.y) << 16);
        unsigned int hi = (unsigned)f2bf(val.z) | ((unsigned)f2bf(val.w) << 16);
        unsigned int off = (unsigned)(n * 120 + c4 * 4);
        *(unsigned int*)(xw + off)     = lo;
        *(unsigned int*)(xw + off + 2) = hi;
    }
    if (tid < 8) xw[192 * 120 + tid] = 0;
    for (int e = tid; e < 192 * 12; e += NT) ks[(e / 12) * 40 + 20 + (e % 12)] = 0;
    for (int e = tid; e < 64 * 12;  e += NT) qs[(e / 12) * 40 + 20 + (e % 12)] = 0;
    for (int e = tid; e < 64 * 40;  e += NT) oh[e] = 0;
    for (int e = tid; e < 2 * 12 * 200; e += NT) {           // vt rows 20..31 (both bufs) = 0
        int b = e / 2400, rr = (e % 2400) / 200, cc = e % 200;
        vt[b * 6400 + (20 + rr) * 200 + cc] = 0;
    }
    if (tid < 64) {                                          // shift-mask region ids
        int ii = tid >> 3, jj = tid & 7;
        int y0 = (wh * 8 + ii + 4) & 255;
        int x0 = (ww * 8 + jj + 4) & 255;
        int hg = (y0 >= 248) + (y0 >= 252);
        int wg = (x0 >= 248) + (x0 >= 252);
        grp_s[tid] = hg * 3 + wg;
    }
    // pred in exact fp32 (sign-sensitive)
    if (tid < 256) {
        int r = tid >> 2, j = tid & 3;
        int ii = r >> 3, jj = r & 7;
        int y0 = (wh * 8 + ii + 4) & 255;
        int x0 = (ww * 8 + jj + 4) & 255;
        const float* xr  = x + (((size_t)(2 * 256 + y0)) * 256 + x0) * 120;
        const float* q0r = quary0 + ((size_t)widx * 64 + r) * 120;
        float acc = 0.f;
        for (int ch = j * 30; ch < j * 30 + 30; ++ch)
            acc += fabsf(xr[ch] - q0r[ch]) * pm_w[ch];
        acc += __shfl_xor(acc, 1);
        acc += __shfl_xor(acc, 2);
        if (j == 0) pred_s[r] = (acc + pm_b[0] >= 0.f) ? 1.f : 0.f;
    }

    f32x4 pacc[8];                               // proj accumulators (waves 4..7)
    #pragma unroll
    for (int i = 0; i < 8; ++i) { f32x4 z = {0.f,0.f,0.f,0.f}; pacc[i] = z; }

    __syncthreads();

    // ---------------- pipelined head loop: A(h) || {B(h) | C(h-1)+proj} ----------------
    for (int h = 0; h < 7; ++h) {
        // ---- phase 1: QKV GEMMs for head h (all 8 waves) ----
        if (h < 6) {
            unsigned short* vtw = vt + (h & 1) * 6400;
            for (int e = wv; e < 44; e += 8) {
                if (e < 36) {
                    int mt = e % 12, nt = e / 12;
                    const unsigned short* arow  = xw + (mt * 16 + l15) * 120;
                    const unsigned short* bbase = KVF + ((h * 3 + nt) * 4) * 512 + ln * 8;
                    f32x4 acc = {0.f, 0.f, 0.f, 0.f};
                    #pragma unroll
                    for (int kk = 0; kk < 4; ++kk) {
                        s16x8 aF = *(const s16x8*)(arow + kk * 32 + qd * 8);
                        s16x8 bF = *(const s16x8*)(bbase + kk * 512);
                        acc = MFMA(aF, bF, acc);
                    }
                    int nglob = nt * 16 + l15;
                    if (nglob < 40) {
                        float bias = qkv_b[nglob < 20 ? (120 + h * 20 + nglob)
                                                      : (240 + h * 20 + nglob - 20)];
                        #pragma unroll
                        for (int reg = 0; reg < 4; ++reg) {
                            int tok = mt * 16 + qd * 4 + reg;
                            unsigned short vb = f2bf(acc[reg] + bias);
                            if (nglob < 20) ks[tok * 40 + nglob] = vb;
                            else            vtw[(nglob - 20) * 200 + tok] = vb;
                        }
                    }
                } else {
                    int t = e - 36, mt = t & 3, nt = t >> 2;
                    const unsigned short* arow  = xw + (128 + mt * 16 + l15) * 120;
                    const unsigned short* bbase = QF + ((h * 2 + nt) * 4) * 512 + ln * 8;
                    f32x4 acc = {0.f, 0.f, 0.f, 0.f};
                    #pragma unroll
                    for (int kk = 0; kk < 4; ++kk) {
                        s16x8 aF = *(const s16x8*)(arow + kk * 32 + qd * 8);
                        s16x8 bF = *(const s16x8*)(bbase + kk * 512);
                        acc = MFMA(aF, bF, acc);
                    }
                    int nn = nt * 16 + l15;
                    if (nn < 20) {
                        float bias = qkv_b[h * 20 + nn];
                        #pragma unroll
                        for (int reg = 0; reg < 4; ++reg)
                            qs[(mt * 16 + qd * 4 + reg) * 40 + nn] = f2bf((acc[reg] + bias) * SCALE);
                    }
                }
            }
        }
        __syncthreads();

        // ---- phase 2: waves 0-3 scores+softmax(h) | waves 4-7 PV+proj(h-1) ----
        if (wv < 4) {
            if (h < 6) {
                const int mt = wv;
                s16x8 aF = *(const s16x8*)(qs + (mt * 16 + l15) * 40 + qd * 8);
                f32x4 sc[12];
                #pragma unroll
                for (int t = 0; t < 12; ++t) {
                    s16x8 bF = *(const s16x8*)(ks + (t * 16 + l15) * 40 + qd * 8);
                    f32x4 z = {0.f, 0.f, 0.f, 0.f};
                    sc[t] = MFMA(aF, bF, z);
                }
                int gk[12];
                #pragma unroll
                for (int t = 0; t < 12; ++t) gk[t] = grp_s[(t * 16 + l15) & 63];
                unsigned short* psw = ps + (h & 1) * 12800;
                #pragma unroll
                for (int reg = 0; reg < 4; ++reg) {
                    int r = mt * 16 + qd * 4 + reg;
                    int gq = grp_s[r];
                    const float* rrow = RPB + (size_t)(h * 64 + r) * 192;
                    float vals[12];
                    float m = -1e30f;
                    #pragma unroll
                    for (int t = 0; t < 12; ++t) {
                        float v = sc[t][reg] + rrow[t * 16 + l15]
                                + ((gq == gk[t]) ? 0.f : -100.f);
                        vals[t] = v; m = fmaxf(m, v);
                    }
                    m = fmaxf(m, __shfl_xor(m, 1));
                    m = fmaxf(m, __shfl_xor(m, 2));
                    m = fmaxf(m, __shfl_xor(m, 4));
                    m = fmaxf(m, __shfl_xor(m, 8));
                    float s = 0.f;
                    #pragma unroll
                    for (int t = 0; t < 12; ++t) {
                        float ev = __expf(vals[t] - m);
                        vals[t] = ev; s += ev;
                    }
                    s += __shfl_xor(s, 1);
                    s += __shfl_xor(s, 2);
                    s += __shfl_xor(s, 4);
                    s += __shfl_xor(s, 8);
                    float inv = 1.0f / s;
                    #pragma unroll
                    for (int t = 0; t < 12; ++t)
                        psw[r * 200 + t * 16 + l15] = f2bf(vals[t] * inv);
                }
            }
        } else if (h > 0) {
            const int hp = h - 1, mtc = wv - 4;
            const unsigned short* psb = ps + (hp & 1) * 12800;
            const unsigned short* vtb = vt + (hp & 1) * 6400;
            #pragma unroll
            for (int ntp = 0; ntp < 2; ++ntp) {
                f32x4 acc = {0.f, 0.f, 0.f, 0.f};
                const unsigned short* prow = psb + (mtc * 16 + l15) * 200;
                const unsigned short* vrow = vtb + (ntp * 16 + l15) * 200;
                #pragma unroll
                for (int kk = 0; kk < 6; ++kk) {
                    s16x8 aF = *(const s16x8*)(prow + kk * 32 + qd * 8);
                    s16x8 bF = *(const s16x8*)(vrow + kk * 32 + qd * 8);
                    acc = MFMA(aF, bF, acc);
                }
                int d = ntp * 16 + l15;
                if (d < 20) {
                    #pragma unroll
                    for (int reg = 0; reg < 4; ++reg)
                        oh[(mtc * 16 + qd * 4 + reg) * 40 + d] = f2bf(acc[reg]);
                }
            }
            // per-head proj partial: intra-wave oh round-trip (own rows only), no barrier
            s16x8 aP = *(const s16x8*)(oh + (mtc * 16 + l15) * 40 + qd * 8);
            #pragma unroll
            for (int nt = 0; nt < 8; ++nt) {
                s16x8 bF = *(const s16x8*)(PJF + (hp * 8 + nt) * 512 + ln * 8);
                pacc[nt] = MFMA(aP, bF, pacc[nt]);
            }
        }
        __syncthreads();
    }

    // ---------------- epilogue: blend + window-reverse + roll scatter ----------------
    if (wv >= 4) {
        const int mtc = wv - 4;
        #pragma unroll
        for (int nt = 0; nt < 8; ++nt) {
            int c = nt * 16 + l15;
            if (c < 120) {
                float pb = proj_b[c];
                #pragma unroll
                for (int reg = 0; reg < 4; ++reg) {
                    int r = mtc * 16 + qd * 4 + reg;
                    float p = pred_s[r];
                    int ii = r >> 3, jj = r & 7;
                    int y0 = (wh * 8 + ii + 4) & 255;
                    int x0 = (ww * 8 + jj + 4) & 255;
                    float fin = (p != 0.f) ? (pacc[nt][reg] + pb)
                                           : quary1[(size_t)widx * 7680 + (size_t)r * 120 + c];
                    out[((size_t)(y0 * 256 + x0)) * 121 + c] = fin;
                }
            }
        }
    }
    if (tid < 64) {
        int r = tid;
        int ii = r >> 3, jj = r & 7;
        int y0 = (wh * 8 + ii + 4) & 255;
        int x0 = (ww * 8 + jj + 4) & 255;
        out[((size_t)(y0 * 256 + x0)) * 121 + 120] = pred_s[r];
    }
}

extern "C" void kernel_launch(void* const* d_in, const int* in_sizes, int n_in,
                              void* d_out, int out_size, void* d_ws, size_t ws_size,
                              hipStream_t stream) {
    const float* x        = (const float*)d_in[0];
    const float* quary0   = (const float*)d_in[1];
    const float* quary1   = (const float*)d_in[2];
    const float* qkv_w    = (const float*)d_in[3];
    const float* qkv_b    = (const float*)d_in[4];
    const float* proj_w   = (const float*)d_in[5];
    const float* proj_b   = (const float*)d_in[6];
    const float* rpb      = (const float*)d_in[7];
    const float* pm_w     = (const float*)d_in[8];
    const float* pm_b     = (const float*)d_in[9];
    const int*   rel_idx  = (const int*)d_in[11];
    float* out = (float*)d_out;
    unsigned char* wsb = (unsigned char*)d_ws;

    prep<<<128, 512, 0, stream>>>(qkv_w, proj_w, rpb, rel_idx, wsb);
    swin_mfma<<<1024, NT, 0, stream>>>(x, quary0, quary1, qkv_b, proj_b,
                                       pm_w, pm_b, wsb, out);
}